// Round 12
// baseline (283.730 us; speedup 1.0000x reference)
//
#include <hip/hip_runtime.h>
#include <math.h>

// ---------------------------------------------------------------------------
// AttentionNet weighted-anchor aggregator.
//   x:  (8, 448, 448, 3) f32
//   wp3:(8, 6, 4, 14, 14) f32   wp4:(8, 6, 4, 7, 7) f32   wp5:(8, 9, 4, 4, 4) f32
//   out:(32, 224, 224, 3) f32 = sum over 21 configs of
//        resize_bilinear( einsum('bkij,bihjwc->bkhwc', w, patches), 224,224 )
//
// agg: 2x2 STRIDED-PAIR tile (this round: h-pairing added to r6's w-pairing).
//   Outputs (h,h+s)x(w,w+s) per thread: x row rb+m*s feeds h with weight
//   w[m] and h+s with w[m-1] -> one px-row of GW+1 loads serves 4 outputs
//   (x-loads per output halved again; FMA/output unchanged). Weight rows
//   staged in LDS with ZERO rows at top/bottom (GH+2 rows) so m-boundary
//   validity is branch-free. k-interleaved [px][k0..k3] layout unchanged.
// rz: 2 k-planes/thread, uint4 taps, compile-time unrolled (r9 body).
// SCHEDULE (r11): H={12..14} G1={0..11} G2={15..18} G3={19..20}
//   agg(H->A); fused(agg G1->B, rz H<-A); fused(agg G2->A, rz G1<-B);
//   fused(agg G3->B, rz G2<-A); rz(G3<-B)
// r11 lesson: fused = sum(parts), not max — schedules are exhausted; only
// body-work reduction moves the total now.
// ---------------------------------------------------------------------------

#define BATCH 8
#define KK 4
#define OUT_HW 224
#define IMG_HW 448
#define NCFG 21

#define WTBL_BYTES (NCFG * 2 * OUT_HW * 16)     // 150528
#define ITBL_BYTES (NCFG * 2 * OUT_HW * 4)      // 37632
#define WT_OFF_BYTES (WTBL_BYTES + ITBL_BYTES)  // 188160
#define WT_F4 12912                             // 8 * (6*196 + 6*49 + 9*16)
#define AGG_OFF_BYTES (WT_OFF_BYTES + WT_F4 * 16)  // 394752 (16B aligned)

#define RZ_GRID (14 * 14 * 16)                  // 3136 resize blocks
#define WPAD_MAX 224                            // (14+2)*14 float4

typedef float v2f __attribute__((ext_vector_type(2)));

// Compile-time cfg geometry (== host double-precision construction; margins
// to int-truncation boundaries are >=0.05 so this is exact).
static constexpr int cKH[NCFG]  = {74,60,49,93,76,62, 148,120,98,186,152,124,
                                   235,192,156,296,241,197,373,304,248};
static constexpr int cKW[NCFG]  = {49,60,74,62,76,93, 98,120,148,124,152,186,
                                   156,192,235,197,241,296,248,304,373};
static constexpr int cMTH[NCFG] = {2,2,2,2,2,2, 2,2,2,2,2,2, 3,2,2,3,3,2,4,3,3};
static constexpr int cMTW[NCFG] = {2,2,2,2,2,2, 2,2,2,2,2,2, 2,2,3,2,3,3,3,3,4};

__host__ __device__ constexpr int ckwp(int c) { return cKW[c] + (cKW[c] & 1); }
// uint2-offset of cfg c's region within its group (layout [b][px][k]).
__host__ __device__ constexpr long cwsoff(int c, int g) {
    long o = 0;
    for (int k = g; k < c; ++k) o += (long)cKH[k] * ckwp(k) * (BATCH * KK);
    return o;
}

struct ACfg {              // agg view of a config
    int kh, kw, kwp, p0, p1;
    int layer;             // 0=p3, 1=p4, 2=p5
    int ns;                // base w-slot count per row (strided pairing)
    int nsh;               // base h-slot count (strided pairing)
    int wt_off;            // float4 offset of transposed weights
    int ws_off;            // uint2 offset in agg region
    int block_start;
    int blocks_per_img;    // ceil(nsh*ns/256)
};

struct AggArgs {
    ACfg e[NCFG];
    int n;
};

struct TablesArgs { int kh[NCFG]; int kw[NCFG]; };

struct TrArgs {
    int layer[NCFG];
    int anchor[NCFG];
    int gsz[NCFG];
    int wt_off[NCFG];
};

struct F3 { float a, b, c; };

__device__ inline unsigned int bf16_rne(float f) {
    unsigned int u = __float_as_uint(f);
    return (u + 0x7fffu + ((u >> 16) & 1u)) >> 16;
}

// ---------------------------------------------------------------------------
// Phase 0a: tap tables. jax.image.resize('bilinear', antialias=True).
// ---------------------------------------------------------------------------
__global__ __launch_bounds__(256) void init_tables(float4* __restrict__ wtbl,
                                                   int* __restrict__ itbl,
                                                   TablesArgs t) {
    int cfg = blockIdx.x >> 1;
    int dim = blockIdx.x & 1;
    int o = threadIdx.x;
    if (o >= OUT_HW) return;
    int n = dim ? t.kw[cfg] : t.kh[cfg];

    float inv = (float)(1.0 / ((double)OUT_HW / (double)n));
    float ks  = inv > 1.f ? inv : 1.f;
    float rks = 1.f / ks;
    float sf  = ((float)o + 0.5f) * inv - 0.5f;
    int i0 = (int)ceilf(sf - ks);  if (i0 < 0) i0 = 0;
    int i1 = (int)floorf(sf + ks); if (i1 > n - 1) i1 = n - 1;
    float sum = 0.f;
    for (int i = i0; i <= i1; ++i) {
        float v = 1.f - fabsf((float)i - sf) * rks;
        sum += (v > 0.f ? v : 0.f);
    }
    float rsum = 1.f / sum;
    float w[4];
#pragma unroll
    for (int d = 0; d < 4; ++d) {
        int i = i0 + d;
        float v = 0.f;
        if (i <= i1) {
            v = 1.f - fabsf((float)i - sf) * rks;
            v = (v > 0.f ? v : 0.f) * rsum;
        }
        w[d] = v;
    }
    int idx = cfg * (2 * OUT_HW) + dim * OUT_HW + o;
    wtbl[idx] = make_float4(w[0], w[1], w[2], w[3]);
    itbl[idx] = i0;
}

// ---------------------------------------------------------------------------
// Phase 0b: transpose weights (B,A,K,gh,gw) -> per cfg [b][g][k0..k3] float4.
// ---------------------------------------------------------------------------
__global__ __launch_bounds__(256) void transpose_w(
        const float* __restrict__ wp3, const float* __restrict__ wp4,
        const float* __restrict__ wp5, float4* __restrict__ wT, TrArgs t) {
    int cfg = blockIdx.x;
    int b = blockIdx.y;
    int gsz = t.gsz[cfg];
    const float* base;
    int A;
    if (t.layer[cfg] == 0)      { base = wp3; A = 6; }
    else if (t.layer[cfg] == 1) { base = wp4; A = 6; }
    else                        { base = wp5; A = 9; }
    const float* src = base + (size_t)(b * A + t.anchor[cfg]) * (KK * gsz);
    for (int g = threadIdx.x; g < gsz; g += 256) {
        wT[t.wt_off[cfg] + b * gsz + g] =
            make_float4(src[0 * gsz + g], src[1 * gsz + g],
                        src[2 * gsz + g], src[3 * gsz + g]);
    }
}

// ---------------------------------------------------------------------------
// Agg body: 2x2 strided tile (h0,h0+S)x(w0,w0+S). w-pair packed in v2f
// lanes; h-pair uses zero-padded weight rows:
//   wlds row r = w[r-1]; row 0 and row GH+1 are ZERO.
//   x row (rb + m*S) feeds h0 with wlds[m+1], h1 with wlds[m].
// ---------------------------------------------------------------------------
template <int GH, int GW, int STRIDE, int L2S>
__device__ inline void agg_body(const ACfg& c, int b, int hs, int ws,
                                const float* __restrict__ xb,
                                const float4* __restrict__ wlds,
                                uint2* __restrict__ agg) {
    const int w0 = ((ws >> L2S) << (L2S + 1)) | (ws & (STRIDE - 1));
    const bool two_w = (w0 + STRIDE) < c.kw;
    const int h0 = ((hs >> L2S) << (L2S + 1)) | (hs & (STRIDE - 1));
    const bool two_h = (h0 + STRIDE) < c.kh;

    v2f acc2[2][4][3];
#pragma unroll
    for (int hh = 0; hh < 2; ++hh)
#pragma unroll
        for (int k = 0; k < 4; ++k)
#pragma unroll
            for (int ch = 0; ch < 3; ++ch) {
                acc2[hh][k][ch].x = 0.f; acc2[hh][k][ch].y = 0.f;
            }

    const int rb = h0 - c.p0;
    int mlo = rb >= 0 ? 0 : (-rb + STRIDE - 1) / STRIDE;
    int mhi = (IMG_HW - 1 - rb) / STRIDE;
    int mcap = two_h ? GH : GH - 1;
    if (mhi > mcap) mhi = mcap;

    const int cb = w0 - c.p1;

    int  cof[GW + 1];
    bool ok [GW + 1];
#pragma unroll
    for (int jj = 0; jj <= GW; ++jj) {
        int col = cb + jj * STRIDE;
        ok[jj] = (unsigned)col < (unsigned)IMG_HW;
        unsigned cc = (unsigned)col;
        if (cc > (unsigned)(IMG_HW - 1)) cc = (unsigned)(IMG_HW - 1);
        cof[jj] = (int)cc * 3;
    }

#pragma unroll 1
    for (int m = mlo; m <= mhi; ++m) {
        const float* xr = xb + (size_t)(rb + m * STRIDE) * (IMG_HW * 3);
        const float4* wr0 = wlds + (m + 1) * GW;   // h0: w[m] (zero at m==GH)
        const float4* wr1 = wlds + m * GW;         // h1: w[m-1] (zero at m==0)

        float px[GW + 1][3];
#pragma unroll
        for (int jj = 0; jj <= GW; ++jj) {
            F3 v = *(const F3*)(xr + cof[jj]);
            px[jj][0] = ok[jj] ? v.a : 0.f;
            px[jj][1] = ok[jj] ? v.b : 0.f;
            px[jj][2] = ok[jj] ? v.c : 0.f;
        }

#pragma unroll
        for (int j = 0; j < GW; ++j) {
            v2f d0 = {px[j][0], px[j + 1][0]};
            v2f d1 = {px[j][1], px[j + 1][1]};
            v2f d2 = {px[j][2], px[j + 1][2]};
            float4 wk0 = wr0[j];
            float4 wk1 = wr1[j];
            {
                v2f wv0 = {wk0.x, wk0.x};
                v2f wv1 = {wk0.y, wk0.y};
                v2f wv2 = {wk0.z, wk0.z};
                v2f wv3 = {wk0.w, wk0.w};
                acc2[0][0][0] = __builtin_elementwise_fma(wv0, d0, acc2[0][0][0]);
                acc2[0][0][1] = __builtin_elementwise_fma(wv0, d1, acc2[0][0][1]);
                acc2[0][0][2] = __builtin_elementwise_fma(wv0, d2, acc2[0][0][2]);
                acc2[0][1][0] = __builtin_elementwise_fma(wv1, d0, acc2[0][1][0]);
                acc2[0][1][1] = __builtin_elementwise_fma(wv1, d1, acc2[0][1][1]);
                acc2[0][1][2] = __builtin_elementwise_fma(wv1, d2, acc2[0][1][2]);
                acc2[0][2][0] = __builtin_elementwise_fma(wv2, d0, acc2[0][2][0]);
                acc2[0][2][1] = __builtin_elementwise_fma(wv2, d1, acc2[0][2][1]);
                acc2[0][2][2] = __builtin_elementwise_fma(wv2, d2, acc2[0][2][2]);
                acc2[0][3][0] = __builtin_elementwise_fma(wv3, d0, acc2[0][3][0]);
                acc2[0][3][1] = __builtin_elementwise_fma(wv3, d1, acc2[0][3][1]);
                acc2[0][3][2] = __builtin_elementwise_fma(wv3, d2, acc2[0][3][2]);
            }
            {
                v2f wv0 = {wk1.x, wk1.x};
                v2f wv1 = {wk1.y, wk1.y};
                v2f wv2 = {wk1.z, wk1.z};
                v2f wv3 = {wk1.w, wk1.w};
                acc2[1][0][0] = __builtin_elementwise_fma(wv0, d0, acc2[1][0][0]);
                acc2[1][0][1] = __builtin_elementwise_fma(wv0, d1, acc2[1][0][1]);
                acc2[1][0][2] = __builtin_elementwise_fma(wv0, d2, acc2[1][0][2]);
                acc2[1][1][0] = __builtin_elementwise_fma(wv1, d0, acc2[1][1][0]);
                acc2[1][1][1] = __builtin_elementwise_fma(wv1, d1, acc2[1][1][1]);
                acc2[1][1][2] = __builtin_elementwise_fma(wv1, d2, acc2[1][1][2]);
                acc2[1][2][0] = __builtin_elementwise_fma(wv2, d0, acc2[1][2][0]);
                acc2[1][2][1] = __builtin_elementwise_fma(wv2, d1, acc2[1][2][1]);
                acc2[1][2][2] = __builtin_elementwise_fma(wv2, d2, acc2[1][2][2]);
                acc2[1][3][0] = __builtin_elementwise_fma(wv3, d0, acc2[1][3][0]);
                acc2[1][3][1] = __builtin_elementwise_fma(wv3, d1, acc2[1][3][1]);
                acc2[1][3][2] = __builtin_elementwise_fma(wv3, d2, acc2[1][3][2]);
            }
        }
    }

    const int npix = c.kh * c.kwp;
#pragma unroll
    for (int hh = 0; hh < 2; ++hh) {
        if (hh == 1 && !two_h) break;
        int h = h0 + hh * STRIDE;
        size_t pb0 = (size_t)c.ws_off
                   + ((size_t)b * npix + (size_t)h * c.kwp + w0) * KK;
        {
            uint4 s0, s1;
            s0.x = bf16_rne(acc2[hh][0][0].x) | (bf16_rne(acc2[hh][0][1].x) << 16);
            s0.y = bf16_rne(acc2[hh][0][2].x);
            s0.z = bf16_rne(acc2[hh][1][0].x) | (bf16_rne(acc2[hh][1][1].x) << 16);
            s0.w = bf16_rne(acc2[hh][1][2].x);
            s1.x = bf16_rne(acc2[hh][2][0].x) | (bf16_rne(acc2[hh][2][1].x) << 16);
            s1.y = bf16_rne(acc2[hh][2][2].x);
            s1.z = bf16_rne(acc2[hh][3][0].x) | (bf16_rne(acc2[hh][3][1].x) << 16);
            s1.w = bf16_rne(acc2[hh][3][2].x);
            *(uint4*)(agg + pb0)     = s0;
            *(uint4*)(agg + pb0 + 2) = s1;
        }
        if (two_w) {
            size_t pb1 = pb0 + (size_t)STRIDE * KK;
            uint4 s0, s1;
            s0.x = bf16_rne(acc2[hh][0][0].y) | (bf16_rne(acc2[hh][0][1].y) << 16);
            s0.y = bf16_rne(acc2[hh][0][2].y);
            s0.z = bf16_rne(acc2[hh][1][0].y) | (bf16_rne(acc2[hh][1][1].y) << 16);
            s0.w = bf16_rne(acc2[hh][1][2].y);
            s1.x = bf16_rne(acc2[hh][2][0].y) | (bf16_rne(acc2[hh][2][1].y) << 16);
            s1.y = bf16_rne(acc2[hh][2][2].y);
            s1.z = bf16_rne(acc2[hh][3][0].y) | (bf16_rne(acc2[hh][3][1].y) << 16);
            s1.w = bf16_rne(acc2[hh][3][2].y);
            *(uint4*)(agg + pb1)     = s0;
            *(uint4*)(agg + pb1 + 2) = s1;
        }
    }
}

// ---------------------------------------------------------------------------
// Agg top (device): cfg lookup + zero-padded weight staging + body dispatch.
// b = local & 7: image-per-XCD (block_start always 8-aligned).
// ---------------------------------------------------------------------------
__device__ inline void agg_top(int bid, const float* __restrict__ x,
                               const float4* __restrict__ wT,
                               uint2* __restrict__ agg, const AggArgs& a,
                               float4* wlds, int tid) {
    int ci = 0;
    while (ci + 1 < a.n && bid >= a.e[ci + 1].block_start) ci++;
    const ACfg c = a.e[ci];
    int local = bid - c.block_start;
    int b     = local & 7;           // image-per-XCD
    int sblk  = local >> 3;

    const int gh = (c.layer == 0) ? 14 : (c.layer == 1) ? 7 : 4;
    const int gsz = gh * gh;
    const int gszp = (gh + 2) * gh;
    for (int t = tid; t < gszp; t += 256) {
        int r = t / gh;
        int cc = t - r * gh;
        float4 v = make_float4(0.f, 0.f, 0.f, 0.f);
        if (r >= 1 && r <= gh)
            v = wT[c.wt_off + b * gsz + (r - 1) * gh + cc];
        wlds[t] = v;
    }
    __syncthreads();

    int pidx = sblk * 256 + tid;
    if (pidx >= c.nsh * c.ns) return;
    int hs = pidx / c.ns;
    int ws = pidx - hs * c.ns;

    const float* __restrict__ xb = x + (size_t)b * (IMG_HW * IMG_HW * 3);
    if (c.layer == 0)      agg_body<14, 14, 32, 5>(c, b, hs, ws, xb, wlds, agg);
    else if (c.layer == 1) agg_body<7, 7, 64, 6>(c, b, hs, ws, xb, wlds, agg);
    else                   agg_body<4, 4, 128, 7>(c, b, hs, ws, xb, wlds, agg);
}

__global__ __launch_bounds__(256, 3) void agg_all(
        const float* __restrict__ x,
        const float4* __restrict__ wT,
        uint2* __restrict__ agg,
        AggArgs a) {
    __shared__ float4 wlds[WPAD_MAX];
    agg_top(blockIdx.x, x, wT, agg, a, wlds, (int)threadIdx.x);
}

// ---------------------------------------------------------------------------
// Tap micro-kernel, 2 k-planes per thread: each tap is ONE uint4 load.
// ---------------------------------------------------------------------------
template <int TH, int TW, int KH_, int KW_, int KWP_>
__device__ inline void taps_ct2(const uint2* __restrict__ pb,
                                int i0, int j0,
                                float4 wh4, float4 ww4,
                                v2f (&a)[3]) {
    const float* wh = (const float*)&wh4;
    const float* ww = (const float*)&ww4;
    uint4 v[TH][TW];
#pragma unroll
    for (int d = 0; d < TH; ++d) {
        int gi = i0 + d;
        if (gi > KH_ - 1) gi = KH_ - 1;
        const uint2* rp = pb + (size_t)gi * (KWP_ * KK);
#pragma unroll
        for (int e = 0; e < TW; ++e) {
            int gj = j0 + e;
            if (gj > KW_ - 1) gj = KW_ - 1;
            v[d][e] = *(const uint4*)(rp + gj * KK);
        }
    }
#pragma unroll
    for (int d = 0; d < TH; ++d) {
        v2f r0 = {0.f, 0.f}, r1 = {0.f, 0.f}, r2 = {0.f, 0.f};
#pragma unroll
        for (int e = 0; e < TW; ++e) {
            uint4 q = v[d][e];
            v2f c0, c1, c2;
            c0.x = __uint_as_float(q.x << 16);
            c0.y = __uint_as_float(q.z << 16);
            c1.x = __uint_as_float(q.x & 0xffff0000u);
            c1.y = __uint_as_float(q.z & 0xffff0000u);
            c2.x = __uint_as_float(q.y << 16);
            c2.y = __uint_as_float(q.w << 16);
            v2f w2 = {ww[e], ww[e]};
            r0 = __builtin_elementwise_fma(w2, c0, r0);
            r1 = __builtin_elementwise_fma(w2, c1, r1);
            r2 = __builtin_elementwise_fma(w2, c2, r2);
        }
        v2f h2 = {wh[d], wh[d]};
        a[0] = __builtin_elementwise_fma(h2, r0, a[0]);
        a[1] = __builtin_elementwise_fma(h2, r1, a[1]);
        a[2] = __builtin_elementwise_fma(h2, r2, a[2]);
    }
}

template <int C, int CEND, int CSTART>
__device__ inline void do_rounds(const uint2* __restrict__ agg,
                                 const float4* __restrict__ wlds,
                                 const int* __restrict__ ilds,
                                 int b, int kp, int tx, int ty,
                                 v2f (&a)[3]) {
    if constexpr (C < CEND) {
        constexpr int li  = C - CSTART;
        constexpr int kh  = cKH[C];
        constexpr int kw  = cKW[C];
        constexpr int kwp = ckwp(C);
        constexpr long wso = cwsoff(C, CSTART);
        float4 wh4 = wlds[li * 32 + ty];
        float4 ww4 = wlds[li * 32 + 16 + tx];
        int i0 = ilds[li * 32 + ty];
        int j0 = ilds[li * 32 + 16 + tx];
        const uint2* pb = agg + wso
                        + (size_t)b * ((size_t)kh * kwp * KK) + kp * 2;
        taps_ct2<cMTH[C], cMTW[C], kh, kw, kwp>(pb, i0, j0, wh4, ww4, a);
        do_rounds<C + 1, CEND, CSTART>(agg, wlds, ilds, b, kp, tx, ty, a);
    }
}

// ---------------------------------------------------------------------------
// Resize top (device): table staging + unrolled rounds. 2 k-planes/thread.
// ---------------------------------------------------------------------------
template <int CSTART, int CEND>
__device__ inline void rz_top(const uint2* __restrict__ agg,
                              const float4* __restrict__ wtbl,
                              const int* __restrict__ itbl,
                              float* __restrict__ out, int accumulate,
                              int bx, int by, int zz, int tid,
                              float4* wlds, int* ilds) {
    constexpr int NC = CEND - CSTART;
    const int tx = tid & 15;
    const int ty = tid >> 4;
    const int xo = bx * 16 + tx;
    const int yo = by * 16 + ty;
    const int b  = zz >> 1;
    const int kp = zz & 1;

    for (int e = tid; e < NC * 32; e += 256) {
        int ci  = e >> 5;
        int r   = e & 31;
        int isW = r >> 4;
        int idx = r & 15;
        int base_o = isW ? (bx * 16) : (by * 16);
        int src = (CSTART + ci) * (2 * OUT_HW) + isW * OUT_HW + base_o + idx;
        wlds[ci * 32 + r] = wtbl[src];
        ilds[ci * 32 + r] = itbl[src];
    }
    __syncthreads();

    size_t obA = ((((size_t)(b * KK + kp * 2)) * OUT_HW + yo) * OUT_HW + xo) * 3;
    size_t obB = obA + (size_t)OUT_HW * OUT_HW * 3;

    v2f a[3];
    if (accumulate) {
        a[0].x = out[obA + 0]; a[0].y = out[obB + 0];
        a[1].x = out[obA + 1]; a[1].y = out[obB + 1];
        a[2].x = out[obA + 2]; a[2].y = out[obB + 2];
    } else {
        a[0] = v2f{0.f, 0.f}; a[1] = v2f{0.f, 0.f}; a[2] = v2f{0.f, 0.f};
    }

    do_rounds<CSTART, CEND, CSTART>(agg, wlds, ilds, b, kp, tx, ty, a);

    out[obA + 0] = a[0].x; out[obA + 1] = a[1].x; out[obA + 2] = a[2].x;
    out[obB + 0] = a[0].y; out[obB + 1] = a[1].y; out[obB + 2] = a[2].y;
}

template <int CSTART, int CEND>
__global__ __launch_bounds__(256, 4) void resize_static(
        const uint2* __restrict__ agg,
        const float4* __restrict__ wtbl,
        const int* __restrict__ itbl,
        float* __restrict__ out,
        int accumulate) {
    constexpr int NC = CEND - CSTART;
    __shared__ float4 wlds[NC * 32];
    __shared__ int    ilds[NC * 32];
    rz_top<CSTART, CEND>(agg, wtbl, itbl, out, accumulate,
                         (int)blockIdx.x, (int)blockIdx.y, (int)blockIdx.z,
                         (int)threadIdx.x, wlds, ilds);
}

// ---------------------------------------------------------------------------
// Fused dispatch: blocks [0,nagg) run agg for the NEXT group (write aggW);
// blocks [nagg, nagg+RZ_GRID) run resize of the PREVIOUS group (read aggR).
// Regions are disjoint (double-buffered), so no intra-kernel sync needed.
// ---------------------------------------------------------------------------
template <int CSTART, int CEND>
__global__ __launch_bounds__(256, 3) void fused_k(
        const float* __restrict__ x,
        const float4* __restrict__ wT,
        uint2* __restrict__ aggW,
        AggArgs a, int naggBlocks,
        const uint2* __restrict__ aggR,
        const float4* __restrict__ wtbl,
        const int* __restrict__ itbl,
        float* __restrict__ out,
        int accumulate) {
    constexpr int NC = CEND - CSTART;
    __shared__ float4 wldsA[WPAD_MAX];
    __shared__ float4 wldsR[NC * 32];
    __shared__ int    ildsR[NC * 32];
    const int tid = (int)threadIdx.x;
    if ((int)blockIdx.x < naggBlocks) {
        agg_top((int)blockIdx.x, x, wT, aggW, a, wldsA, tid);
    } else {
        int rid = (int)blockIdx.x - naggBlocks;
        int bx = rid % 14;
        int t2 = rid / 14;
        int by = t2 % 14;
        int zz = t2 / 14;
        rz_top<CSTART, CEND>(aggR, wtbl, itbl, out, accumulate,
                             bx, by, zz, tid, wldsR, ildsR);
    }
}

// ---------------------------------------------------------------------------
// Host launch
// ---------------------------------------------------------------------------
extern "C" void kernel_launch(void* const* d_in, const int* in_sizes, int n_in,
                              void* d_out, int out_size, void* d_ws, size_t ws_size,
                              hipStream_t stream) {
    const float* x   = (const float*)d_in[0];
    const float* wp3 = (const float*)d_in[1];
    const float* wp4 = (const float*)d_in[2];
    const float* wp5 = (const float*)d_in[3];
    float* out = (float*)d_out;
    float4* wtbl = (float4*)d_ws;
    int*    itbl = (int*)((char*)d_ws + WTBL_BYTES);
    float4* wT   = (float4*)((char*)d_ws + WT_OFF_BYTES);
    uint2*  agg  = (uint2*)((char*)d_ws + AGG_OFF_BYTES);

    // Build the 21 configs exactly as the reference does (double precision).
    struct { int stride, size, nscale; double scales[3]; int gh; } layers[3] = {
        {32, 48, 2, {pow(2.0, 1.0 / 3.0), pow(2.0, 2.0 / 3.0), 0.0}, 14},
        {64, 96, 2, {pow(2.0, 1.0 / 3.0), pow(2.0, 2.0 / 3.0), 0.0}, 7},
        {128, 192, 3, {1.0, pow(2.0, 1.0 / 3.0), pow(2.0, 2.0 / 3.0)}, 4},
    };
    const double ars[3] = {0.667, 1.0, 1.5};

    struct HostCfg {
        int kh, kw, kwp, stride, p0, p1, gh, gw, layer, anchor, wt_off;
        int ns, nsh, blocks_per_img;
    } cfg[NCFG];
    TablesArgs ta;
    TrArgs tr;
    int nc = 0, wt_run = 0;
    for (int L = 0; L < 3; ++L) {
        int anchor = 0;
        for (int si = 0; si < layers[L].nscale; ++si) {
            for (int ai = 0; ai < 3; ++ai) {
                double ss = (double)layers[L].size * layers[L].scales[si];
                double sq = pow(ars[ai], 0.5);
                int kh = (int)(ss / sq);
                int kw = (int)(ss * sq);
                HostCfg& e = cfg[nc];
                e.kh = kh; e.kw = kw;
                e.kwp = kw + (kw & 1);
                e.stride = layers[L].stride;
                e.p0 = (int)ceil((double)(kh - layers[L].stride) / 2.0);
                e.p1 = (int)ceil((double)(kw - layers[L].stride) / 2.0);
                e.gh = layers[L].gh; e.gw = layers[L].gh;
                e.layer = L; e.anchor = anchor++;
                int s = e.stride;
                {   // base w-slot count
                    int q = kw / s, r = kw % s;
                    e.ns = ((q + 1) / 2) * s + ((q % 2 == 0) ? r : 0);
                }
                {   // base h-slot count
                    int q = kh / s, r = kh % s;
                    e.nsh = ((q + 1) / 2) * s + ((q % 2 == 0) ? r : 0);
                }
                e.blocks_per_img = (e.nsh * e.ns + 255) / 256;
                e.wt_off = wt_run;
                int gsz = e.gh * e.gw;
                wt_run += BATCH * gsz;
                ta.kh[nc] = kh; ta.kw[nc] = kw;
                tr.layer[nc] = L; tr.anchor[nc] = e.anchor;
                tr.gsz[nc] = gsz; tr.wt_off[nc] = e.wt_off;
                ++nc;
            }
        }
    }

    init_tables<<<NCFG * 2, 256, 0, stream>>>(wtbl, itbl, ta);
    transpose_w<<<dim3(NCFG, BATCH), 256, 0, stream>>>(wp3, wp4, wp5, wT, tr);

    auto build = [&](int gstart, int gend, AggArgs& aa) -> int {
        aa.n = 0;
        int ablocks = 0;
        size_t off = 0;
        for (int c = gstart; c < gend; ++c) {
            ACfg& lc = aa.e[aa.n++];
            lc.kh = cfg[c].kh; lc.kw = cfg[c].kw; lc.kwp = cfg[c].kwp;
            lc.p0 = cfg[c].p0; lc.p1 = cfg[c].p1;
            lc.layer = cfg[c].layer;
            lc.ns = cfg[c].ns;
            lc.nsh = cfg[c].nsh;
            lc.wt_off = cfg[c].wt_off;
            lc.ws_off = (int)off;
            lc.block_start = ablocks;
            lc.blocks_per_img = cfg[c].blocks_per_img;
            ablocks += cfg[c].blocks_per_img * BATCH;
            off += (size_t)cfg[c].kh * cfg[c].kwp * (BATCH * KK);
        }
        return ablocks;
    };
    auto gpx = [&](int gstart, int gend) -> size_t {
        size_t p = 0;
        for (int c = gstart; c < gend; ++c)
            p += (size_t)cfg[c].kh * cfg[c].kwp;
        return p * (BATCH * KK);
    };

    // Schedule: H={12..14} G1={0..11} G2={15..18} G3={19..20}.
    // A holds H then G2; B holds G1 then G3.
    size_t pxH = gpx(12, 15), px1 = gpx(0, 12), px2 = gpx(15, 19),
           px3 = gpx(19, 21);
    size_t pxA = pxH > px2 ? pxH : px2;
    size_t pxB = px1 > px3 ? px1 : px3;
    bool can_overlap =
        (size_t)AGG_OFF_BYTES + (pxA + pxB) * sizeof(uint2) <= ws_size;

    dim3 rgrid(14, 14, 16);

    if (can_overlap) {
        uint2* bufA = agg;
        uint2* bufB = agg + pxA;
        AggArgs aH, a1, a2, a3;
        int nH = build(12, 15, aH);
        int n1 = build(0, 12, a1);
        int n2 = build(15, 19, a2);
        int n3 = build(19, 21, a3);

        agg_all<<<nH, 256, 0, stream>>>(x, wT, bufA, aH);
        fused_k<12, 15><<<n1 + RZ_GRID, 256, 0, stream>>>(
            x, wT, bufB, a1, n1, bufA, wtbl, itbl, out, 0);
        fused_k<0, 12><<<n2 + RZ_GRID, 256, 0, stream>>>(
            x, wT, bufA, a2, n2, bufB, wtbl, itbl, out, 1);
        fused_k<15, 19><<<n3 + RZ_GRID, 256, 0, stream>>>(
            x, wT, bufB, a3, n3, bufA, wtbl, itbl, out, 1);
        resize_static<19, 21><<<rgrid, 256, 0, stream>>>(
            bufB, wtbl, itbl, out, 1);
    } else {
        // Serial fallback: same 4 groups, single buffer.
        AggArgs aa;
        int nb;
        nb = build(12, 15, aa);
        agg_all<<<nb, 256, 0, stream>>>(x, wT, agg, aa);
        resize_static<12, 15><<<rgrid, 256, 0, stream>>>(agg, wtbl, itbl, out, 0);
        nb = build(0, 12, aa);
        agg_all<<<nb, 256, 0, stream>>>(x, wT, agg, aa);
        resize_static<0, 12><<<rgrid, 256, 0, stream>>>(agg, wtbl, itbl, out, 1);
        nb = build(15, 19, aa);
        agg_all<<<nb, 256, 0, stream>>>(x, wT, agg, aa);
        resize_static<15, 19><<<rgrid, 256, 0, stream>>>(agg, wtbl, itbl, out, 1);
        nb = build(19, 21, aa);
        agg_all<<<nb, 256, 0, stream>>>(x, wT, agg, aa);
        resize_static<19, 21><<<rgrid, 256, 0, stream>>>(agg, wtbl, itbl, out, 1);
    }
    (void)in_sizes; (void)n_in; (void)out_size;
}

// Round 13
// 281.179 us; speedup vs baseline: 1.0091x; 1.0091x over previous
//
#include <hip/hip_runtime.h>
#include <math.h>

// ---------------------------------------------------------------------------
// AttentionNet weighted-anchor aggregator.
//   x:  (8, 448, 448, 3) f32
//   wp3:(8, 6, 4, 14, 14) f32   wp4:(8, 6, 4, 7, 7) f32   wp5:(8, 9, 4, 4, 4) f32
//   out:(32, 224, 224, 3) f32 = sum over 21 configs of
//        resize_bilinear( einsum('bkij,bihjwc->bkhwc', w, patches), 224,224 )
//
// Bodies = round-9/11 exactly (r12's 2x2 h-pairing regressed: VGPR 72,
// occupancy 27%, +100K bank conflicts — latency regime punishes per-thread
// state growth more than load-halving pays):
//   agg = strided w-pair, masked clamped loads, k-interleaved [px][k0..k3];
//   rz  = 2 k-planes/thread, uint4 taps, compile-time unrolled rounds.
// SCHEDULE (r11): H={12..14} G1={0..11} G2={15..18} G3={19..20}
//   agg(H->A); fused(agg G1->B, rz H<-A); fused(agg G2->A, rz G1<-B);
//   fused(agg G3->B, rz G2<-A); rz(G3<-B)
// Session finding: total ≈ Σ body work (~125 agg + ~135 rz); three schedules
// within ±2us; both bodies latency-bound with all cheap structural levers
// exhausted. This file restores the verified best (266.1 us).
// ---------------------------------------------------------------------------

#define BATCH 8
#define KK 4
#define OUT_HW 224
#define IMG_HW 448
#define NCFG 21

#define WTBL_BYTES (NCFG * 2 * OUT_HW * 16)     // 150528
#define ITBL_BYTES (NCFG * 2 * OUT_HW * 4)      // 37632
#define WT_OFF_BYTES (WTBL_BYTES + ITBL_BYTES)  // 188160
#define WT_F4 12912                             // 8 * (6*196 + 6*49 + 9*16)
#define AGG_OFF_BYTES (WT_OFF_BYTES + WT_F4 * 16)  // 394752 (16B aligned)

#define RZ_GRID (14 * 14 * 16)                  // 3136 resize blocks

typedef float v2f __attribute__((ext_vector_type(2)));

// Compile-time cfg geometry (== host double-precision construction; margins
// to int-truncation boundaries are >=0.05 so this is exact).
static constexpr int cKH[NCFG]  = {74,60,49,93,76,62, 148,120,98,186,152,124,
                                   235,192,156,296,241,197,373,304,248};
static constexpr int cKW[NCFG]  = {49,60,74,62,76,93, 98,120,148,124,152,186,
                                   156,192,235,197,241,296,248,304,373};
static constexpr int cMTH[NCFG] = {2,2,2,2,2,2, 2,2,2,2,2,2, 3,2,2,3,3,2,4,3,3};
static constexpr int cMTW[NCFG] = {2,2,2,2,2,2, 2,2,2,2,2,2, 2,2,3,2,3,3,3,3,4};

__host__ __device__ constexpr int ckwp(int c) { return cKW[c] + (cKW[c] & 1); }
// uint2-offset of cfg c's region within its group (layout [b][px][k]).
__host__ __device__ constexpr long cwsoff(int c, int g) {
    long o = 0;
    for (int k = g; k < c; ++k) o += (long)cKH[k] * ckwp(k) * (BATCH * KK);
    return o;
}

struct ACfg {              // agg view of a config
    int kh, kw, kwp, p0, p1;
    int layer;             // 0=p3, 1=p4, 2=p5
    int ns;                // base-slot count per row (strided pairing)
    int wt_off;            // float4 offset of transposed weights
    int ws_off;            // uint2 offset in agg region
    int block_start;
    int blocks_per_img;    // ceil(kh*ns/256)
};

struct AggArgs {
    ACfg e[NCFG];
    int n;
};

struct TablesArgs { int kh[NCFG]; int kw[NCFG]; };

struct TrArgs {
    int layer[NCFG];
    int anchor[NCFG];
    int gsz[NCFG];
    int wt_off[NCFG];
};

struct F3 { float a, b, c; };

__device__ inline unsigned int bf16_rne(float f) {
    unsigned int u = __float_as_uint(f);
    return (u + 0x7fffu + ((u >> 16) & 1u)) >> 16;
}

// ---------------------------------------------------------------------------
// Phase 0a: tap tables. jax.image.resize('bilinear', antialias=True).
// ---------------------------------------------------------------------------
__global__ __launch_bounds__(256) void init_tables(float4* __restrict__ wtbl,
                                                   int* __restrict__ itbl,
                                                   TablesArgs t) {
    int cfg = blockIdx.x >> 1;
    int dim = blockIdx.x & 1;
    int o = threadIdx.x;
    if (o >= OUT_HW) return;
    int n = dim ? t.kw[cfg] : t.kh[cfg];

    float inv = (float)(1.0 / ((double)OUT_HW / (double)n));
    float ks  = inv > 1.f ? inv : 1.f;
    float rks = 1.f / ks;
    float sf  = ((float)o + 0.5f) * inv - 0.5f;
    int i0 = (int)ceilf(sf - ks);  if (i0 < 0) i0 = 0;
    int i1 = (int)floorf(sf + ks); if (i1 > n - 1) i1 = n - 1;
    float sum = 0.f;
    for (int i = i0; i <= i1; ++i) {
        float v = 1.f - fabsf((float)i - sf) * rks;
        sum += (v > 0.f ? v : 0.f);
    }
    float rsum = 1.f / sum;
    float w[4];
#pragma unroll
    for (int d = 0; d < 4; ++d) {
        int i = i0 + d;
        float v = 0.f;
        if (i <= i1) {
            v = 1.f - fabsf((float)i - sf) * rks;
            v = (v > 0.f ? v : 0.f) * rsum;
        }
        w[d] = v;
    }
    int idx = cfg * (2 * OUT_HW) + dim * OUT_HW + o;
    wtbl[idx] = make_float4(w[0], w[1], w[2], w[3]);
    itbl[idx] = i0;
}

// ---------------------------------------------------------------------------
// Phase 0b: transpose weights (B,A,K,gh,gw) -> per cfg [b][g][k0..k3] float4.
// ---------------------------------------------------------------------------
__global__ __launch_bounds__(256) void transpose_w(
        const float* __restrict__ wp3, const float* __restrict__ wp4,
        const float* __restrict__ wp5, float4* __restrict__ wT, TrArgs t) {
    int cfg = blockIdx.x;
    int b = blockIdx.y;
    int gsz = t.gsz[cfg];
    const float* base;
    int A;
    if (t.layer[cfg] == 0)      { base = wp3; A = 6; }
    else if (t.layer[cfg] == 1) { base = wp4; A = 6; }
    else                        { base = wp5; A = 9; }
    const float* src = base + (size_t)(b * A + t.anchor[cfg]) * (KK * gsz);
    for (int g = threadIdx.x; g < gsz; g += 256) {
        wT[t.wt_off[cfg] + b * gsz + g] =
            make_float4(src[0 * gsz + g], src[1 * gsz + g],
                        src[2 * gsz + g], src[3 * gsz + g]);
    }
}

// ---------------------------------------------------------------------------
// Agg body: strided-pair outputs (w0, w0+STRIDE) packed as v2f lanes;
// k-interleaved epilogue (two uint4 stores per px).
// ---------------------------------------------------------------------------
template <int GH, int GW, int STRIDE, int L2S>
__device__ inline void agg_body(const ACfg& c, int b, int h, int slot,
                                const float* __restrict__ xb,
                                const float4* __restrict__ wlds,
                                uint2* __restrict__ agg) {
    const int w0 = (((slot >> L2S) << (L2S + 1)) | (slot & (STRIDE - 1)));
    const int w1 = w0 + STRIDE;
    const bool two = w1 < c.kw;

    v2f acc2[4][3];
#pragma unroll
    for (int k = 0; k < 4; ++k)
#pragma unroll
        for (int ch = 0; ch < 3; ++ch) { acc2[k][ch].x = 0.f; acc2[k][ch].y = 0.f; }

    const int rb = h - c.p0;
    int ilo = rb >= 0 ? 0 : (-rb + STRIDE - 1) / STRIDE;
    int ihi = (IMG_HW - 1 - rb) / STRIDE;
    if (ihi > GH - 1) ihi = GH - 1;

    const int cb = w0 - c.p1;

    int  cof[GW + 1];
    bool ok [GW + 1];
#pragma unroll
    for (int jj = 0; jj <= GW; ++jj) {
        int col = cb + jj * STRIDE;
        ok[jj] = (unsigned)col < (unsigned)IMG_HW;
        unsigned cc = (unsigned)col;
        if (cc > (unsigned)(IMG_HW - 1)) cc = (unsigned)(IMG_HW - 1);
        cof[jj] = (int)cc * 3;
    }

#pragma unroll 1
    for (int i = ilo; i <= ihi; ++i) {
        const float* xr = xb + (size_t)(rb + i * STRIDE) * (IMG_HW * 3);
        const float4* wrow = wlds + i * GW;

        float px[GW + 1][3];
#pragma unroll
        for (int jj = 0; jj <= GW; ++jj) {
            F3 v = *(const F3*)(xr + cof[jj]);
            px[jj][0] = ok[jj] ? v.a : 0.f;
            px[jj][1] = ok[jj] ? v.b : 0.f;
            px[jj][2] = ok[jj] ? v.c : 0.f;
        }

#pragma unroll
        for (int j = 0; j < GW; ++j) {
            float4 wk = wrow[j];
            v2f d0 = {px[j][0], px[j + 1][0]};
            v2f d1 = {px[j][1], px[j + 1][1]};
            v2f d2 = {px[j][2], px[j + 1][2]};
            v2f wv0 = {wk.x, wk.x};
            v2f wv1 = {wk.y, wk.y};
            v2f wv2 = {wk.z, wk.z};
            v2f wv3 = {wk.w, wk.w};
            acc2[0][0] = __builtin_elementwise_fma(wv0, d0, acc2[0][0]);
            acc2[0][1] = __builtin_elementwise_fma(wv0, d1, acc2[0][1]);
            acc2[0][2] = __builtin_elementwise_fma(wv0, d2, acc2[0][2]);
            acc2[1][0] = __builtin_elementwise_fma(wv1, d0, acc2[1][0]);
            acc2[1][1] = __builtin_elementwise_fma(wv1, d1, acc2[1][1]);
            acc2[1][2] = __builtin_elementwise_fma(wv1, d2, acc2[1][2]);
            acc2[2][0] = __builtin_elementwise_fma(wv2, d0, acc2[2][0]);
            acc2[2][1] = __builtin_elementwise_fma(wv2, d1, acc2[2][1]);
            acc2[2][2] = __builtin_elementwise_fma(wv2, d2, acc2[2][2]);
            acc2[3][0] = __builtin_elementwise_fma(wv3, d0, acc2[3][0]);
            acc2[3][1] = __builtin_elementwise_fma(wv3, d1, acc2[3][1]);
            acc2[3][2] = __builtin_elementwise_fma(wv3, d2, acc2[3][2]);
        }
    }

    const int npix = c.kh * c.kwp;
    size_t pb0 = (size_t)c.ws_off
               + ((size_t)b * npix + (size_t)h * c.kwp + w0) * KK;
    {
        uint4 s0, s1;
        s0.x = bf16_rne(acc2[0][0].x) | (bf16_rne(acc2[0][1].x) << 16);
        s0.y = bf16_rne(acc2[0][2].x);
        s0.z = bf16_rne(acc2[1][0].x) | (bf16_rne(acc2[1][1].x) << 16);
        s0.w = bf16_rne(acc2[1][2].x);
        s1.x = bf16_rne(acc2[2][0].x) | (bf16_rne(acc2[2][1].x) << 16);
        s1.y = bf16_rne(acc2[2][2].x);
        s1.z = bf16_rne(acc2[3][0].x) | (bf16_rne(acc2[3][1].x) << 16);
        s1.w = bf16_rne(acc2[3][2].x);
        *(uint4*)(agg + pb0)     = s0;
        *(uint4*)(agg + pb0 + 2) = s1;
    }
    if (two) {
        size_t pb1 = pb0 + (size_t)STRIDE * KK;
        uint4 s0, s1;
        s0.x = bf16_rne(acc2[0][0].y) | (bf16_rne(acc2[0][1].y) << 16);
        s0.y = bf16_rne(acc2[0][2].y);
        s0.z = bf16_rne(acc2[1][0].y) | (bf16_rne(acc2[1][1].y) << 16);
        s0.w = bf16_rne(acc2[1][2].y);
        s1.x = bf16_rne(acc2[2][0].y) | (bf16_rne(acc2[2][1].y) << 16);
        s1.y = bf16_rne(acc2[2][2].y);
        s1.z = bf16_rne(acc2[3][0].y) | (bf16_rne(acc2[3][1].y) << 16);
        s1.w = bf16_rne(acc2[3][2].y);
        *(uint4*)(agg + pb1)     = s0;
        *(uint4*)(agg + pb1 + 2) = s1;
    }
}

// ---------------------------------------------------------------------------
// Agg top (device): cfg lookup + weight staging + body dispatch.
// b = local & 7: image-per-XCD (block_start always 8-aligned).
// ---------------------------------------------------------------------------
__device__ inline void agg_top(int bid, const float* __restrict__ x,
                               const float4* __restrict__ wT,
                               uint2* __restrict__ agg, const AggArgs& a,
                               float4* wlds, int tid) {
    int ci = 0;
    while (ci + 1 < a.n && bid >= a.e[ci + 1].block_start) ci++;
    const ACfg c = a.e[ci];
    int local = bid - c.block_start;
    int b     = local & 7;           // image-per-XCD
    int sblk  = local >> 3;

    const int gsz = (c.layer == 0) ? 196 : (c.layer == 1) ? 49 : 16;
    for (int t = tid; t < gsz; t += 256)
        wlds[t] = wT[c.wt_off + b * gsz + t];
    __syncthreads();

    int pidx = sblk * 256 + tid;
    if (pidx >= c.kh * c.ns) return;
    int h    = pidx / c.ns;
    int slot = pidx - h * c.ns;

    const float* __restrict__ xb = x + (size_t)b * (IMG_HW * IMG_HW * 3);
    if (c.layer == 0)      agg_body<14, 14, 32, 5>(c, b, h, slot, xb, wlds, agg);
    else if (c.layer == 1) agg_body<7, 7, 64, 6>(c, b, h, slot, xb, wlds, agg);
    else                   agg_body<4, 4, 128, 7>(c, b, h, slot, xb, wlds, agg);
}

__global__ __launch_bounds__(256, 3) void agg_all(
        const float* __restrict__ x,
        const float4* __restrict__ wT,
        uint2* __restrict__ agg,
        AggArgs a) {
    __shared__ float4 wlds[196];
    agg_top(blockIdx.x, x, wT, agg, a, wlds, (int)threadIdx.x);
}

// ---------------------------------------------------------------------------
// Tap micro-kernel, 2 k-planes per thread: each tap is ONE uint4 load.
// ---------------------------------------------------------------------------
template <int TH, int TW, int KH_, int KW_, int KWP_>
__device__ inline void taps_ct2(const uint2* __restrict__ pb,
                                int i0, int j0,
                                float4 wh4, float4 ww4,
                                v2f (&a)[3]) {
    const float* wh = (const float*)&wh4;
    const float* ww = (const float*)&ww4;
    uint4 v[TH][TW];
#pragma unroll
    for (int d = 0; d < TH; ++d) {
        int gi = i0 + d;
        if (gi > KH_ - 1) gi = KH_ - 1;
        const uint2* rp = pb + (size_t)gi * (KWP_ * KK);
#pragma unroll
        for (int e = 0; e < TW; ++e) {
            int gj = j0 + e;
            if (gj > KW_ - 1) gj = KW_ - 1;
            v[d][e] = *(const uint4*)(rp + gj * KK);
        }
    }
#pragma unroll
    for (int d = 0; d < TH; ++d) {
        v2f r0 = {0.f, 0.f}, r1 = {0.f, 0.f}, r2 = {0.f, 0.f};
#pragma unroll
        for (int e = 0; e < TW; ++e) {
            uint4 q = v[d][e];
            v2f c0, c1, c2;
            c0.x = __uint_as_float(q.x << 16);
            c0.y = __uint_as_float(q.z << 16);
            c1.x = __uint_as_float(q.x & 0xffff0000u);
            c1.y = __uint_as_float(q.z & 0xffff0000u);
            c2.x = __uint_as_float(q.y << 16);
            c2.y = __uint_as_float(q.w << 16);
            v2f w2 = {ww[e], ww[e]};
            r0 = __builtin_elementwise_fma(w2, c0, r0);
            r1 = __builtin_elementwise_fma(w2, c1, r1);
            r2 = __builtin_elementwise_fma(w2, c2, r2);
        }
        v2f h2 = {wh[d], wh[d]};
        a[0] = __builtin_elementwise_fma(h2, r0, a[0]);
        a[1] = __builtin_elementwise_fma(h2, r1, a[1]);
        a[2] = __builtin_elementwise_fma(h2, r2, a[2]);
    }
}

template <int C, int CEND, int CSTART>
__device__ inline void do_rounds(const uint2* __restrict__ agg,
                                 const float4* __restrict__ wlds,
                                 const int* __restrict__ ilds,
                                 int b, int kp, int tx, int ty,
                                 v2f (&a)[3]) {
    if constexpr (C < CEND) {
        constexpr int li  = C - CSTART;
        constexpr int kh  = cKH[C];
        constexpr int kw  = cKW[C];
        constexpr int kwp = ckwp(C);
        constexpr long wso = cwsoff(C, CSTART);
        float4 wh4 = wlds[li * 32 + ty];
        float4 ww4 = wlds[li * 32 + 16 + tx];
        int i0 = ilds[li * 32 + ty];
        int j0 = ilds[li * 32 + 16 + tx];
        const uint2* pb = agg + wso
                        + (size_t)b * ((size_t)kh * kwp * KK) + kp * 2;
        taps_ct2<cMTH[C], cMTW[C], kh, kw, kwp>(pb, i0, j0, wh4, ww4, a);
        do_rounds<C + 1, CEND, CSTART>(agg, wlds, ilds, b, kp, tx, ty, a);
    }
}

// ---------------------------------------------------------------------------
// Resize top (device): table staging + unrolled rounds. 2 k-planes/thread.
// ---------------------------------------------------------------------------
template <int CSTART, int CEND>
__device__ inline void rz_top(const uint2* __restrict__ agg,
                              const float4* __restrict__ wtbl,
                              const int* __restrict__ itbl,
                              float* __restrict__ out, int accumulate,
                              int bx, int by, int zz, int tid,
                              float4* wlds, int* ilds) {
    constexpr int NC = CEND - CSTART;
    const int tx = tid & 15;
    const int ty = tid >> 4;
    const int xo = bx * 16 + tx;
    const int yo = by * 16 + ty;
    const int b  = zz >> 1;
    const int kp = zz & 1;

    for (int e = tid; e < NC * 32; e += 256) {
        int ci  = e >> 5;
        int r   = e & 31;
        int isW = r >> 4;
        int idx = r & 15;
        int base_o = isW ? (bx * 16) : (by * 16);
        int src = (CSTART + ci) * (2 * OUT_HW) + isW * OUT_HW + base_o + idx;
        wlds[ci * 32 + r] = wtbl[src];
        ilds[ci * 32 + r] = itbl[src];
    }
    __syncthreads();

    size_t obA = ((((size_t)(b * KK + kp * 2)) * OUT_HW + yo) * OUT_HW + xo) * 3;
    size_t obB = obA + (size_t)OUT_HW * OUT_HW * 3;

    v2f a[3];
    if (accumulate) {
        a[0].x = out[obA + 0]; a[0].y = out[obB + 0];
        a[1].x = out[obA + 1]; a[1].y = out[obB + 1];
        a[2].x = out[obA + 2]; a[2].y = out[obB + 2];
    } else {
        a[0] = v2f{0.f, 0.f}; a[1] = v2f{0.f, 0.f}; a[2] = v2f{0.f, 0.f};
    }

    do_rounds<CSTART, CEND, CSTART>(agg, wlds, ilds, b, kp, tx, ty, a);

    out[obA + 0] = a[0].x; out[obA + 1] = a[1].x; out[obA + 2] = a[2].x;
    out[obB + 0] = a[0].y; out[obB + 1] = a[1].y; out[obB + 2] = a[2].y;
}

template <int CSTART, int CEND>
__global__ __launch_bounds__(256, 4) void resize_static(
        const uint2* __restrict__ agg,
        const float4* __restrict__ wtbl,
        const int* __restrict__ itbl,
        float* __restrict__ out,
        int accumulate) {
    constexpr int NC = CEND - CSTART;
    __shared__ float4 wlds[NC * 32];
    __shared__ int    ilds[NC * 32];
    rz_top<CSTART, CEND>(agg, wtbl, itbl, out, accumulate,
                         (int)blockIdx.x, (int)blockIdx.y, (int)blockIdx.z,
                         (int)threadIdx.x, wlds, ilds);
}

// ---------------------------------------------------------------------------
// Fused dispatch: blocks [0,nagg) run agg for the NEXT group (write aggW);
// blocks [nagg, nagg+RZ_GRID) run resize of the PREVIOUS group (read aggR).
// Regions are disjoint (double-buffered), so no intra-kernel sync needed.
// ---------------------------------------------------------------------------
template <int CSTART, int CEND>
__global__ __launch_bounds__(256, 3) void fused_k(
        const float* __restrict__ x,
        const float4* __restrict__ wT,
        uint2* __restrict__ aggW,
        AggArgs a, int naggBlocks,
        const uint2* __restrict__ aggR,
        const float4* __restrict__ wtbl,
        const int* __restrict__ itbl,
        float* __restrict__ out,
        int accumulate) {
    constexpr int NC = CEND - CSTART;
    __shared__ float4 wldsA[196];
    __shared__ float4 wldsR[NC * 32];
    __shared__ int    ildsR[NC * 32];
    const int tid = (int)threadIdx.x;
    if ((int)blockIdx.x < naggBlocks) {
        agg_top((int)blockIdx.x, x, wT, aggW, a, wldsA, tid);
    } else {
        int rid = (int)blockIdx.x - naggBlocks;
        int bx = rid % 14;
        int t2 = rid / 14;
        int by = t2 % 14;
        int zz = t2 / 14;
        rz_top<CSTART, CEND>(aggR, wtbl, itbl, out, accumulate,
                             bx, by, zz, tid, wldsR, ildsR);
    }
}

// ---------------------------------------------------------------------------
// Host launch
// ---------------------------------------------------------------------------
extern "C" void kernel_launch(void* const* d_in, const int* in_sizes, int n_in,
                              void* d_out, int out_size, void* d_ws, size_t ws_size,
                              hipStream_t stream) {
    const float* x   = (const float*)d_in[0];
    const float* wp3 = (const float*)d_in[1];
    const float* wp4 = (const float*)d_in[2];
    const float* wp5 = (const float*)d_in[3];
    float* out = (float*)d_out;
    float4* wtbl = (float4*)d_ws;
    int*    itbl = (int*)((char*)d_ws + WTBL_BYTES);
    float4* wT   = (float4*)((char*)d_ws + WT_OFF_BYTES);
    uint2*  agg  = (uint2*)((char*)d_ws + AGG_OFF_BYTES);

    // Build the 21 configs exactly as the reference does (double precision).
    struct { int stride, size, nscale; double scales[3]; int gh; } layers[3] = {
        {32, 48, 2, {pow(2.0, 1.0 / 3.0), pow(2.0, 2.0 / 3.0), 0.0}, 14},
        {64, 96, 2, {pow(2.0, 1.0 / 3.0), pow(2.0, 2.0 / 3.0), 0.0}, 7},
        {128, 192, 3, {1.0, pow(2.0, 1.0 / 3.0), pow(2.0, 2.0 / 3.0)}, 4},
    };
    const double ars[3] = {0.667, 1.0, 1.5};

    struct HostCfg {
        int kh, kw, kwp, stride, p0, p1, gh, gw, layer, anchor, wt_off;
        int ns, blocks_per_img;
    } cfg[NCFG];
    TablesArgs ta;
    TrArgs tr;
    int nc = 0, wt_run = 0;
    for (int L = 0; L < 3; ++L) {
        int anchor = 0;
        for (int si = 0; si < layers[L].nscale; ++si) {
            for (int ai = 0; ai < 3; ++ai) {
                double ss = (double)layers[L].size * layers[L].scales[si];
                double sq = pow(ars[ai], 0.5);
                int kh = (int)(ss / sq);
                int kw = (int)(ss * sq);
                HostCfg& e = cfg[nc];
                e.kh = kh; e.kw = kw;
                e.kwp = kw + (kw & 1);
                e.stride = layers[L].stride;
                e.p0 = (int)ceil((double)(kh - layers[L].stride) / 2.0);
                e.p1 = (int)ceil((double)(kw - layers[L].stride) / 2.0);
                e.gh = layers[L].gh; e.gw = layers[L].gh;
                e.layer = L; e.anchor = anchor++;
                int s = e.stride;
                int q = kw / s, r = kw % s;
                e.ns = ((q + 1) / 2) * s + ((q % 2 == 0) ? r : 0);
                e.blocks_per_img = (kh * e.ns + 255) / 256;
                e.wt_off = wt_run;
                int gsz = e.gh * e.gw;
                wt_run += BATCH * gsz;
                ta.kh[nc] = kh; ta.kw[nc] = kw;
                tr.layer[nc] = L; tr.anchor[nc] = e.anchor;
                tr.gsz[nc] = gsz; tr.wt_off[nc] = e.wt_off;
                ++nc;
            }
        }
    }

    init_tables<<<NCFG * 2, 256, 0, stream>>>(wtbl, itbl, ta);
    transpose_w<<<dim3(NCFG, BATCH), 256, 0, stream>>>(wp3, wp4, wp5, wT, tr);

    auto build = [&](int gstart, int gend, AggArgs& aa) -> int {
        aa.n = 0;
        int ablocks = 0;
        size_t off = 0;
        for (int c = gstart; c < gend; ++c) {
            ACfg& lc = aa.e[aa.n++];
            lc.kh = cfg[c].kh; lc.kw = cfg[c].kw; lc.kwp = cfg[c].kwp;
            lc.p0 = cfg[c].p0; lc.p1 = cfg[c].p1;
            lc.layer = cfg[c].layer;
            lc.ns = cfg[c].ns;
            lc.wt_off = cfg[c].wt_off;
            lc.ws_off = (int)off;
            lc.block_start = ablocks;
            lc.blocks_per_img = cfg[c].blocks_per_img;
            ablocks += cfg[c].blocks_per_img * BATCH;
            off += (size_t)cfg[c].kh * cfg[c].kwp * (BATCH * KK);
        }
        return ablocks;
    };
    auto gpx = [&](int gstart, int gend) -> size_t {
        size_t p = 0;
        for (int c = gstart; c < gend; ++c)
            p += (size_t)cfg[c].kh * cfg[c].kwp;
        return p * (BATCH * KK);
    };

    // Schedule: H={12..14} G1={0..11} G2={15..18} G3={19..20}.
    // A holds H then G2; B holds G1 then G3.
    size_t pxH = gpx(12, 15), px1 = gpx(0, 12), px2 = gpx(15, 19),
           px3 = gpx(19, 21);
    size_t pxA = pxH > px2 ? pxH : px2;
    size_t pxB = px1 > px3 ? px1 : px3;
    bool can_overlap =
        (size_t)AGG_OFF_BYTES + (pxA + pxB) * sizeof(uint2) <= ws_size;

    dim3 rgrid(14, 14, 16);

    if (can_overlap) {
        uint2* bufA = agg;
        uint2* bufB = agg + pxA;
        AggArgs aH, a1, a2, a3;
        int nH = build(12, 15, aH);
        int n1 = build(0, 12, a1);
        int n2 = build(15, 19, a2);
        int n3 = build(19, 21, a3);

        agg_all<<<nH, 256, 0, stream>>>(x, wT, bufA, aH);
        fused_k<12, 15><<<n1 + RZ_GRID, 256, 0, stream>>>(
            x, wT, bufB, a1, n1, bufA, wtbl, itbl, out, 0);
        fused_k<0, 12><<<n2 + RZ_GRID, 256, 0, stream>>>(
            x, wT, bufA, a2, n2, bufB, wtbl, itbl, out, 1);
        fused_k<15, 19><<<n3 + RZ_GRID, 256, 0, stream>>>(
            x, wT, bufB, a3, n3, bufA, wtbl, itbl, out, 1);
        resize_static<19, 21><<<rgrid, 256, 0, stream>>>(
            bufB, wtbl, itbl, out, 1);
    } else {
        // Serial fallback: same 4 groups, single buffer.
        AggArgs aa;
        int nb;
        nb = build(12, 15, aa);
        agg_all<<<nb, 256, 0, stream>>>(x, wT, agg, aa);
        resize_static<12, 15><<<rgrid, 256, 0, stream>>>(agg, wtbl, itbl, out, 0);
        nb = build(0, 12, aa);
        agg_all<<<nb, 256, 0, stream>>>(x, wT, agg, aa);
        resize_static<0, 12><<<rgrid, 256, 0, stream>>>(agg, wtbl, itbl, out, 1);
        nb = build(15, 19, aa);
        agg_all<<<nb, 256, 0, stream>>>(x, wT, agg, aa);
        resize_static<15, 19><<<rgrid, 256, 0, stream>>>(agg, wtbl, itbl, out, 1);
        nb = build(19, 21, aa);
        agg_all<<<nb, 256, 0, stream>>>(x, wT, agg, aa);
        resize_static<19, 21><<<rgrid, 256, 0, stream>>>(agg, wtbl, itbl, out, 1);
    }
    (void)in_sizes; (void)n_in; (void)out_size;
}

// Round 15
// 272.630 us; speedup vs baseline: 1.0407x; 1.0314x over previous
//
#include <hip/hip_runtime.h>
#include <math.h>

// ---------------------------------------------------------------------------
// AttentionNet weighted-anchor aggregator.
//   x:  (8, 448, 448, 3) f32
//   wp3:(8, 6, 4, 14, 14) f32   wp4:(8, 6, 4, 7, 7) f32   wp5:(8, 9, 4, 4, 4) f32
//   out:(32, 224, 224, 3) f32 = sum over 21 configs of
//        resize_bilinear( einsum('bkij,bihjwc->bkhwc', w, patches), 224,224 )
//
// agg = r9/r11 body: strided w-pair, masked clamped loads, k-interleaved
//       [px][k0..k3] (32B per px).
// rz  = K-QUAD (resubmit of r14; infra failure, never measured): ONE thread
//       handles all 4 k of its output px. With the 32B/px layout, the old
//       kp=0/kp=1 block split fetched the SAME 64B line twice (two px per
//       line, different CUs). Quad merge halves rz line traffic (same
//       mechanism as r7's winning k-pair merge).
//       Block = 256 thr, 32x8 px tile, z = b (8 planes), RZ_GRID 1568;
//       tables = 40 entries/cfg (8 h + 32 w); acc = 3 x v4f.
// SCHEDULE (r11): H={12..14} G1={0..11} G2={15..18} G3={19..20}
//   agg(H->A); fused(agg G1->B, rz H<-A); fused(agg G2->A, rz G1<-B);
//   fused(agg G3->B, rz G2<-A); rz(G3<-B)
// ---------------------------------------------------------------------------

#define BATCH 8
#define KK 4
#define OUT_HW 224
#define IMG_HW 448
#define NCFG 21

#define WTBL_BYTES (NCFG * 2 * OUT_HW * 16)     // 150528
#define ITBL_BYTES (NCFG * 2 * OUT_HW * 4)      // 37632
#define WT_OFF_BYTES (WTBL_BYTES + ITBL_BYTES)  // 188160
#define WT_F4 12912                             // 8 * (6*196 + 6*49 + 9*16)
#define AGG_OFF_BYTES (WT_OFF_BYTES + WT_F4 * 16)  // 394752 (16B aligned)

#define RZ_GRID (7 * 28 * 8)                    // 1568 resize blocks (32x8 tiles)
#define TBL_STRIDE 40                           // 8 h + 32 w entries per cfg

typedef float v2f __attribute__((ext_vector_type(2)));
typedef float v4f __attribute__((ext_vector_type(4)));

// Compile-time cfg geometry (== host double-precision construction; margins
// to int-truncation boundaries are >=0.05 so this is exact).
static constexpr int cKH[NCFG]  = {74,60,49,93,76,62, 148,120,98,186,152,124,
                                   235,192,156,296,241,197,373,304,248};
static constexpr int cKW[NCFG]  = {49,60,74,62,76,93, 98,120,148,124,152,186,
                                   156,192,235,197,241,296,248,304,373};
static constexpr int cMTH[NCFG] = {2,2,2,2,2,2, 2,2,2,2,2,2, 3,2,2,3,3,2,4,3,3};
static constexpr int cMTW[NCFG] = {2,2,2,2,2,2, 2,2,2,2,2,2, 2,2,3,2,3,3,3,3,4};

__host__ __device__ constexpr int ckwp(int c) { return cKW[c] + (cKW[c] & 1); }
// uint2-offset of cfg c's region within its group (layout [b][px][k]).
__host__ __device__ constexpr long cwsoff(int c, int g) {
    long o = 0;
    for (int k = g; k < c; ++k) o += (long)cKH[k] * ckwp(k) * (BATCH * KK);
    return o;
}

struct ACfg {              // agg view of a config
    int kh, kw, kwp, p0, p1;
    int layer;             // 0=p3, 1=p4, 2=p5
    int ns;                // base-slot count per row (strided pairing)
    int wt_off;            // float4 offset of transposed weights
    int ws_off;            // uint2 offset in agg region
    int block_start;
    int blocks_per_img;    // ceil(kh*ns/256)
};

struct AggArgs {
    ACfg e[NCFG];
    int n;
};

struct TablesArgs { int kh[NCFG]; int kw[NCFG]; };

struct TrArgs {
    int layer[NCFG];
    int anchor[NCFG];
    int gsz[NCFG];
    int wt_off[NCFG];
};

struct F3 { float a, b, c; };

__device__ inline unsigned int bf16_rne(float f) {
    unsigned int u = __float_as_uint(f);
    return (u + 0x7fffu + ((u >> 16) & 1u)) >> 16;
}

// ---------------------------------------------------------------------------
// Phase 0a: tap tables. jax.image.resize('bilinear', antialias=True).
// ---------------------------------------------------------------------------
__global__ __launch_bounds__(256) void init_tables(float4* __restrict__ wtbl,
                                                   int* __restrict__ itbl,
                                                   TablesArgs t) {
    int cfg = blockIdx.x >> 1;
    int dim = blockIdx.x & 1;
    int o = threadIdx.x;
    if (o >= OUT_HW) return;
    int n = dim ? t.kw[cfg] : t.kh[cfg];

    float inv = (float)(1.0 / ((double)OUT_HW / (double)n));
    float ks  = inv > 1.f ? inv : 1.f;
    float rks = 1.f / ks;
    float sf  = ((float)o + 0.5f) * inv - 0.5f;
    int i0 = (int)ceilf(sf - ks);  if (i0 < 0) i0 = 0;
    int i1 = (int)floorf(sf + ks); if (i1 > n - 1) i1 = n - 1;
    float sum = 0.f;
    for (int i = i0; i <= i1; ++i) {
        float v = 1.f - fabsf((float)i - sf) * rks;
        sum += (v > 0.f ? v : 0.f);
    }
    float rsum = 1.f / sum;
    float w[4];
#pragma unroll
    for (int d = 0; d < 4; ++d) {
        int i = i0 + d;
        float v = 0.f;
        if (i <= i1) {
            v = 1.f - fabsf((float)i - sf) * rks;
            v = (v > 0.f ? v : 0.f) * rsum;
        }
        w[d] = v;
    }
    int idx = cfg * (2 * OUT_HW) + dim * OUT_HW + o;
    wtbl[idx] = make_float4(w[0], w[1], w[2], w[3]);
    itbl[idx] = i0;
}

// ---------------------------------------------------------------------------
// Phase 0b: transpose weights (B,A,K,gh,gw) -> per cfg [b][g][k0..k3] float4.
// ---------------------------------------------------------------------------
__global__ __launch_bounds__(256) void transpose_w(
        const float* __restrict__ wp3, const float* __restrict__ wp4,
        const float* __restrict__ wp5, float4* __restrict__ wT, TrArgs t) {
    int cfg = blockIdx.x;
    int b = blockIdx.y;
    int gsz = t.gsz[cfg];
    const float* base;
    int A;
    if (t.layer[cfg] == 0)      { base = wp3; A = 6; }
    else if (t.layer[cfg] == 1) { base = wp4; A = 6; }
    else                        { base = wp5; A = 9; }
    const float* src = base + (size_t)(b * A + t.anchor[cfg]) * (KK * gsz);
    for (int g = threadIdx.x; g < gsz; g += 256) {
        wT[t.wt_off[cfg] + b * gsz + g] =
            make_float4(src[0 * gsz + g], src[1 * gsz + g],
                        src[2 * gsz + g], src[3 * gsz + g]);
    }
}

// ---------------------------------------------------------------------------
// Agg body: strided-pair outputs (w0, w0+STRIDE) packed as v2f lanes;
// k-interleaved epilogue (two uint4 stores per px).
// ---------------------------------------------------------------------------
template <int GH, int GW, int STRIDE, int L2S>
__device__ inline void agg_body(const ACfg& c, int b, int h, int slot,
                                const float* __restrict__ xb,
                                const float4* __restrict__ wlds,
                                uint2* __restrict__ agg) {
    const int w0 = (((slot >> L2S) << (L2S + 1)) | (slot & (STRIDE - 1)));
    const int w1 = w0 + STRIDE;
    const bool two = w1 < c.kw;

    v2f acc2[4][3];
#pragma unroll
    for (int k = 0; k < 4; ++k)
#pragma unroll
        for (int ch = 0; ch < 3; ++ch) { acc2[k][ch].x = 0.f; acc2[k][ch].y = 0.f; }

    const int rb = h - c.p0;
    int ilo = rb >= 0 ? 0 : (-rb + STRIDE - 1) / STRIDE;
    int ihi = (IMG_HW - 1 - rb) / STRIDE;
    if (ihi > GH - 1) ihi = GH - 1;

    const int cb = w0 - c.p1;

    int  cof[GW + 1];
    bool ok [GW + 1];
#pragma unroll
    for (int jj = 0; jj <= GW; ++jj) {
        int col = cb + jj * STRIDE;
        ok[jj] = (unsigned)col < (unsigned)IMG_HW;
        unsigned cc = (unsigned)col;
        if (cc > (unsigned)(IMG_HW - 1)) cc = (unsigned)(IMG_HW - 1);
        cof[jj] = (int)cc * 3;
    }

#pragma unroll 1
    for (int i = ilo; i <= ihi; ++i) {
        const float* xr = xb + (size_t)(rb + i * STRIDE) * (IMG_HW * 3);
        const float4* wrow = wlds + i * GW;

        float px[GW + 1][3];
#pragma unroll
        for (int jj = 0; jj <= GW; ++jj) {
            F3 v = *(const F3*)(xr + cof[jj]);
            px[jj][0] = ok[jj] ? v.a : 0.f;
            px[jj][1] = ok[jj] ? v.b : 0.f;
            px[jj][2] = ok[jj] ? v.c : 0.f;
        }

#pragma unroll
        for (int j = 0; j < GW; ++j) {
            float4 wk = wrow[j];
            v2f d0 = {px[j][0], px[j + 1][0]};
            v2f d1 = {px[j][1], px[j + 1][1]};
            v2f d2 = {px[j][2], px[j + 1][2]};
            v2f wv0 = {wk.x, wk.x};
            v2f wv1 = {wk.y, wk.y};
            v2f wv2 = {wk.z, wk.z};
            v2f wv3 = {wk.w, wk.w};
            acc2[0][0] = __builtin_elementwise_fma(wv0, d0, acc2[0][0]);
            acc2[0][1] = __builtin_elementwise_fma(wv0, d1, acc2[0][1]);
            acc2[0][2] = __builtin_elementwise_fma(wv0, d2, acc2[0][2]);
            acc2[1][0] = __builtin_elementwise_fma(wv1, d0, acc2[1][0]);
            acc2[1][1] = __builtin_elementwise_fma(wv1, d1, acc2[1][1]);
            acc2[1][2] = __builtin_elementwise_fma(wv1, d2, acc2[1][2]);
            acc2[2][0] = __builtin_elementwise_fma(wv2, d0, acc2[2][0]);
            acc2[2][1] = __builtin_elementwise_fma(wv2, d1, acc2[2][1]);
            acc2[2][2] = __builtin_elementwise_fma(wv2, d2, acc2[2][2]);
            acc2[3][0] = __builtin_elementwise_fma(wv3, d0, acc2[3][0]);
            acc2[3][1] = __builtin_elementwise_fma(wv3, d1, acc2[3][1]);
            acc2[3][2] = __builtin_elementwise_fma(wv3, d2, acc2[3][2]);
        }
    }

    const int npix = c.kh * c.kwp;
    size_t pb0 = (size_t)c.ws_off
               + ((size_t)b * npix + (size_t)h * c.kwp + w0) * KK;
    {
        uint4 s0, s1;
        s0.x = bf16_rne(acc2[0][0].x) | (bf16_rne(acc2[0][1].x) << 16);
        s0.y = bf16_rne(acc2[0][2].x);
        s0.z = bf16_rne(acc2[1][0].x) | (bf16_rne(acc2[1][1].x) << 16);
        s0.w = bf16_rne(acc2[1][2].x);
        s1.x = bf16_rne(acc2[2][0].x) | (bf16_rne(acc2[2][1].x) << 16);
        s1.y = bf16_rne(acc2[2][2].x);
        s1.z = bf16_rne(acc2[3][0].x) | (bf16_rne(acc2[3][1].x) << 16);
        s1.w = bf16_rne(acc2[3][2].x);
        *(uint4*)(agg + pb0)     = s0;
        *(uint4*)(agg + pb0 + 2) = s1;
    }
    if (two) {
        size_t pb1 = pb0 + (size_t)STRIDE * KK;
        uint4 s0, s1;
        s0.x = bf16_rne(acc2[0][0].y) | (bf16_rne(acc2[0][1].y) << 16);
        s0.y = bf16_rne(acc2[0][2].y);
        s0.z = bf16_rne(acc2[1][0].y) | (bf16_rne(acc2[1][1].y) << 16);
        s0.w = bf16_rne(acc2[1][2].y);
        s1.x = bf16_rne(acc2[2][0].y) | (bf16_rne(acc2[2][1].y) << 16);
        s1.y = bf16_rne(acc2[2][2].y);
        s1.z = bf16_rne(acc2[3][0].y) | (bf16_rne(acc2[3][1].y) << 16);
        s1.w = bf16_rne(acc2[3][2].y);
        *(uint4*)(agg + pb1)     = s0;
        *(uint4*)(agg + pb1 + 2) = s1;
    }
}

// ---------------------------------------------------------------------------
// Agg top (device): cfg lookup + weight staging + body dispatch.
// b = local & 7: image-per-XCD (block_start always 8-aligned).
// ---------------------------------------------------------------------------
__device__ inline void agg_top(int bid, const float* __restrict__ x,
                               const float4* __restrict__ wT,
                               uint2* __restrict__ agg, const AggArgs& a,
                               float4* wlds, int tid) {
    int ci = 0;
    while (ci + 1 < a.n && bid >= a.e[ci + 1].block_start) ci++;
    const ACfg c = a.e[ci];
    int local = bid - c.block_start;
    int b     = local & 7;           // image-per-XCD
    int sblk  = local >> 3;

    const int gsz = (c.layer == 0) ? 196 : (c.layer == 1) ? 49 : 16;
    for (int t = tid; t < gsz; t += 256)
        wlds[t] = wT[c.wt_off + b * gsz + t];
    __syncthreads();

    int pidx = sblk * 256 + tid;
    if (pidx >= c.kh * c.ns) return;
    int h    = pidx / c.ns;
    int slot = pidx - h * c.ns;

    const float* __restrict__ xb = x + (size_t)b * (IMG_HW * IMG_HW * 3);
    if (c.layer == 0)      agg_body<14, 14, 32, 5>(c, b, h, slot, xb, wlds, agg);
    else if (c.layer == 1) agg_body<7, 7, 64, 6>(c, b, h, slot, xb, wlds, agg);
    else                   agg_body<4, 4, 128, 7>(c, b, h, slot, xb, wlds, agg);
}

__global__ __launch_bounds__(256, 3) void agg_all(
        const float* __restrict__ x,
        const float4* __restrict__ wT,
        uint2* __restrict__ agg,
        AggArgs a) {
    __shared__ float4 wlds[196];
    agg_top(blockIdx.x, x, wT, agg, a, wlds, (int)threadIdx.x);
}

// ---------------------------------------------------------------------------
// Tap micro-kernel, ALL 4 k-planes per thread: each tap is two adjacent
// uint4 loads (one 64B-line px pair), accumulated with packed fma on v4f.
// ---------------------------------------------------------------------------
template <int TH, int TW, int KH_, int KW_, int KWP_>
__device__ inline void taps_ct4(const uint2* __restrict__ pb,
                                int i0, int j0,
                                float4 wh4, float4 ww4,
                                v4f (&a)[3]) {
    const float* wh = (const float*)&wh4;
    const float* ww = (const float*)&ww4;
    uint4 v0[TH][TW], v1[TH][TW];
#pragma unroll
    for (int d = 0; d < TH; ++d) {
        int gi = i0 + d;
        if (gi > KH_ - 1) gi = KH_ - 1;
        const uint2* rp = pb + (size_t)gi * (KWP_ * KK);
#pragma unroll
        for (int e = 0; e < TW; ++e) {
            int gj = j0 + e;
            if (gj > KW_ - 1) gj = KW_ - 1;
            v0[d][e] = *(const uint4*)(rp + gj * KK);
            v1[d][e] = *(const uint4*)(rp + gj * KK + 2);
        }
    }
#pragma unroll
    for (int d = 0; d < TH; ++d) {
        v4f r0 = {0.f, 0.f, 0.f, 0.f};
        v4f r1 = {0.f, 0.f, 0.f, 0.f};
        v4f r2 = {0.f, 0.f, 0.f, 0.f};
#pragma unroll
        for (int e = 0; e < TW; ++e) {
            uint4 qa = v0[d][e];
            uint4 qb = v1[d][e];
            v4f c0, c1, c2;
            c0.x = __uint_as_float(qa.x << 16);
            c0.y = __uint_as_float(qa.z << 16);
            c0.z = __uint_as_float(qb.x << 16);
            c0.w = __uint_as_float(qb.z << 16);
            c1.x = __uint_as_float(qa.x & 0xffff0000u);
            c1.y = __uint_as_float(qa.z & 0xffff0000u);
            c1.z = __uint_as_float(qb.x & 0xffff0000u);
            c1.w = __uint_as_float(qb.z & 0xffff0000u);
            c2.x = __uint_as_float(qa.y << 16);
            c2.y = __uint_as_float(qa.w << 16);
            c2.z = __uint_as_float(qb.y << 16);
            c2.w = __uint_as_float(qb.w << 16);
            v4f w4 = {ww[e], ww[e], ww[e], ww[e]};
            r0 = __builtin_elementwise_fma(w4, c0, r0);
            r1 = __builtin_elementwise_fma(w4, c1, r1);
            r2 = __builtin_elementwise_fma(w4, c2, r2);
        }
        v4f h4 = {wh[d], wh[d], wh[d], wh[d]};
        a[0] = __builtin_elementwise_fma(h4, r0, a[0]);
        a[1] = __builtin_elementwise_fma(h4, r1, a[1]);
        a[2] = __builtin_elementwise_fma(h4, r2, a[2]);
    }
}

template <int C, int CEND, int CSTART>
__device__ inline void do_rounds(const uint2* __restrict__ agg,
                                 const float4* __restrict__ wlds,
                                 const int* __restrict__ ilds,
                                 int b, int tx, int ty,
                                 v4f (&a)[3]) {
    if constexpr (C < CEND) {
        constexpr int li  = C - CSTART;
        constexpr int kh  = cKH[C];
        constexpr int kw  = cKW[C];
        constexpr int kwp = ckwp(C);
        constexpr long wso = cwsoff(C, CSTART);
        float4 wh4 = wlds[li * TBL_STRIDE + ty];
        float4 ww4 = wlds[li * TBL_STRIDE + 8 + tx];
        int i0 = ilds[li * TBL_STRIDE + ty];
        int j0 = ilds[li * TBL_STRIDE + 8 + tx];
        const uint2* pb = agg + wso + (size_t)b * ((size_t)kh * kwp * KK);
        taps_ct4<cMTH[C], cMTW[C], kh, kw, kwp>(pb, i0, j0, wh4, ww4, a);
        do_rounds<C + 1, CEND, CSTART>(agg, wlds, ilds, b, tx, ty, a);
    }
}

// ---------------------------------------------------------------------------
// Resize top (device): 32x8 px tile, one thread = one px, ALL 4 k-planes.
// Tables: TBL_STRIDE entries/cfg (8 h rows + 32 w cols).
// ---------------------------------------------------------------------------
template <int CSTART, int CEND>
__device__ inline void rz_top(const uint2* __restrict__ agg,
                              const float4* __restrict__ wtbl,
                              const int* __restrict__ itbl,
                              float* __restrict__ out, int accumulate,
                              int bx, int by, int b, int tid,
                              float4* wlds, int* ilds) {
    constexpr int NC = CEND - CSTART;
    const int tx = tid & 31;
    const int ty = tid >> 5;
    const int xo = bx * 32 + tx;
    const int yo = by * 8 + ty;

    for (int e = tid; e < NC * TBL_STRIDE; e += 256) {
        int ci  = e / TBL_STRIDE;
        int r   = e - ci * TBL_STRIDE;
        int isW = r >= 8;
        int idx = isW ? (r - 8) : r;
        int base_o = isW ? (bx * 32) : (by * 8);
        int src = (CSTART + ci) * (2 * OUT_HW) + (isW ? OUT_HW : 0)
                + base_o + idx;
        wlds[ci * TBL_STRIDE + r] = wtbl[src];
        ilds[ci * TBL_STRIDE + r] = itbl[src];
    }
    __syncthreads();

    const size_t plane = (size_t)OUT_HW * OUT_HW * 3;
    size_t ob0 = ((((size_t)(b * KK)) * OUT_HW + yo) * OUT_HW + xo) * 3;

    v4f a[3];
    if (accumulate) {
#pragma unroll
        for (int ch = 0; ch < 3; ++ch) {
            a[ch].x = out[ob0 + 0 * plane + ch];
            a[ch].y = out[ob0 + 1 * plane + ch];
            a[ch].z = out[ob0 + 2 * plane + ch];
            a[ch].w = out[ob0 + 3 * plane + ch];
        }
    } else {
#pragma unroll
        for (int ch = 0; ch < 3; ++ch)
            a[ch] = v4f{0.f, 0.f, 0.f, 0.f};
    }

    do_rounds<CSTART, CEND, CSTART>(agg, wlds, ilds, b, tx, ty, a);

#pragma unroll
    for (int ch = 0; ch < 3; ++ch) {
        out[ob0 + 0 * plane + ch] = a[ch].x;
        out[ob0 + 1 * plane + ch] = a[ch].y;
        out[ob0 + 2 * plane + ch] = a[ch].z;
        out[ob0 + 3 * plane + ch] = a[ch].w;
    }
}

// rid 0..RZ_GRID-1 -> (bx, by, b): bx in [0,7), by in [0,28), b in [0,8).
__device__ inline void rz_decomp(int rid, int& bx, int& by, int& b) {
    bx = rid % 7;
    int t2 = rid / 7;
    by = t2 % 28;
    b  = t2 / 28;
}

template <int CSTART, int CEND>
__global__ __launch_bounds__(256, 4) void resize_static(
        const uint2* __restrict__ agg,
        const float4* __restrict__ wtbl,
        const int* __restrict__ itbl,
        float* __restrict__ out,
        int accumulate) {
    constexpr int NC = CEND - CSTART;
    __shared__ float4 wlds[NC * TBL_STRIDE];
    __shared__ int    ilds[NC * TBL_STRIDE];
    int bx, by, b;
    rz_decomp((int)blockIdx.x, bx, by, b);
    rz_top<CSTART, CEND>(agg, wtbl, itbl, out, accumulate,
                         bx, by, b, (int)threadIdx.x, wlds, ilds);
}

// ---------------------------------------------------------------------------
// Fused dispatch: blocks [0,nagg) run agg for the NEXT group (write aggW);
// blocks [nagg, nagg+RZ_GRID) run resize of the PREVIOUS group (read aggR).
// Regions are disjoint (double-buffered), so no intra-kernel sync needed.
// ---------------------------------------------------------------------------
template <int CSTART, int CEND>
__global__ __launch_bounds__(256, 3) void fused_k(
        const float* __restrict__ x,
        const float4* __restrict__ wT,
        uint2* __restrict__ aggW,
        AggArgs a, int naggBlocks,
        const uint2* __restrict__ aggR,
        const float4* __restrict__ wtbl,
        const int* __restrict__ itbl,
        float* __restrict__ out,
        int accumulate) {
    constexpr int NC = CEND - CSTART;
    __shared__ float4 wldsA[196];
    __shared__ float4 wldsR[NC * TBL_STRIDE];
    __shared__ int    ildsR[NC * TBL_STRIDE];
    const int tid = (int)threadIdx.x;
    if ((int)blockIdx.x < naggBlocks) {
        agg_top((int)blockIdx.x, x, wT, aggW, a, wldsA, tid);
    } else {
        int bx, by, b;
        rz_decomp((int)blockIdx.x - naggBlocks, bx, by, b);
        rz_top<CSTART, CEND>(aggR, wtbl, itbl, out, accumulate,
                             bx, by, b, tid, wldsR, ildsR);
    }
}

// ---------------------------------------------------------------------------
// Host launch
// ---------------------------------------------------------------------------
extern "C" void kernel_launch(void* const* d_in, const int* in_sizes, int n_in,
                              void* d_out, int out_size, void* d_ws, size_t ws_size,
                              hipStream_t stream) {
    const float* x   = (const float*)d_in[0];
    const float* wp3 = (const float*)d_in[1];
    const float* wp4 = (const float*)d_in[2];
    const float* wp5 = (const float*)d_in[3];
    float* out = (float*)d_out;
    float4* wtbl = (float4*)d_ws;
    int*    itbl = (int*)((char*)d_ws + WTBL_BYTES);
    float4* wT   = (float4*)((char*)d_ws + WT_OFF_BYTES);
    uint2*  agg  = (uint2*)((char*)d_ws + AGG_OFF_BYTES);

    // Build the 21 configs exactly as the reference does (double precision).
    struct { int stride, size, nscale; double scales[3]; int gh; } layers[3] = {
        {32, 48, 2, {pow(2.0, 1.0 / 3.0), pow(2.0, 2.0 / 3.0), 0.0}, 14},
        {64, 96, 2, {pow(2.0, 1.0 / 3.0), pow(2.0, 2.0 / 3.0), 0.0}, 7},
        {128, 192, 3, {1.0, pow(2.0, 1.0 / 3.0), pow(2.0, 2.0 / 3.0)}, 4},
    };
    const double ars[3] = {0.667, 1.0, 1.5};

    struct HostCfg {
        int kh, kw, kwp, stride, p0, p1, gh, gw, layer, anchor, wt_off;
        int ns, blocks_per_img;
    } cfg[NCFG];
    TablesArgs ta;
    TrArgs tr;
    int nc = 0, wt_run = 0;
    for (int L = 0; L < 3; ++L) {
        int anchor = 0;
        for (int si = 0; si < layers[L].nscale; ++si) {
            for (int ai = 0; ai < 3; ++ai) {
                double ss = (double)layers[L].size * layers[L].scales[si];
                double sq = pow(ars[ai], 0.5);
                int kh = (int)(ss / sq);
                int kw = (int)(ss * sq);
                HostCfg& e = cfg[nc];
                e.kh = kh; e.kw = kw;
                e.kwp = kw + (kw & 1);
                e.stride = layers[L].stride;
                e.p0 = (int)ceil((double)(kh - layers[L].stride) / 2.0);
                e.p1 = (int)ceil((double)(kw - layers[L].stride) / 2.0);
                e.gh = layers[L].gh; e.gw = layers[L].gh;
                e.layer = L; e.anchor = anchor++;
                int s = e.stride;
                int q = kw / s, r = kw % s;
                e.ns = ((q + 1) / 2) * s + ((q % 2 == 0) ? r : 0);
                e.blocks_per_img = (kh * e.ns + 255) / 256;
                e.wt_off = wt_run;
                int gsz = e.gh * e.gw;
                wt_run += BATCH * gsz;
                ta.kh[nc] = kh; ta.kw[nc] = kw;
                tr.layer[nc] = L; tr.anchor[nc] = e.anchor;
                tr.gsz[nc] = gsz; tr.wt_off[nc] = e.wt_off;
                ++nc;
            }
        }
    }

    init_tables<<<NCFG * 2, 256, 0, stream>>>(wtbl, itbl, ta);
    transpose_w<<<dim3(NCFG, BATCH), 256, 0, stream>>>(wp3, wp4, wp5, wT, tr);

    auto build = [&](int gstart, int gend, AggArgs& aa) -> int {
        aa.n = 0;
        int ablocks = 0;
        size_t off = 0;
        for (int c = gstart; c < gend; ++c) {
            ACfg& lc = aa.e[aa.n++];
            lc.kh = cfg[c].kh; lc.kw = cfg[c].kw; lc.kwp = cfg[c].kwp;
            lc.p0 = cfg[c].p0; lc.p1 = cfg[c].p1;
            lc.layer = cfg[c].layer;
            lc.ns = cfg[c].ns;
            lc.wt_off = cfg[c].wt_off;
            lc.ws_off = (int)off;
            lc.block_start = ablocks;
            lc.blocks_per_img = cfg[c].blocks_per_img;
            ablocks += cfg[c].blocks_per_img * BATCH;
            off += (size_t)cfg[c].kh * cfg[c].kwp * (BATCH * KK);
        }
        return ablocks;
    };
    auto gpx = [&](int gstart, int gend) -> size_t {
        size_t p = 0;
        for (int c = gstart; c < gend; ++c)
            p += (size_t)cfg[c].kh * cfg[c].kwp;
        return p * (BATCH * KK);
    };

    // Schedule: H={12..14} G1={0..11} G2={15..18} G3={19..20}.
    // A holds H then G2; B holds G1 then G3.
    size_t pxH = gpx(12, 15), px1 = gpx(0, 12), px2 = gpx(15, 19),
           px3 = gpx(19, 21);
    size_t pxA = pxH > px2 ? pxH : px2;
    size_t pxB = px1 > px3 ? px1 : px3;
    bool can_overlap =
        (size_t)AGG_OFF_BYTES + (pxA + pxB) * sizeof(uint2) <= ws_size;

    if (can_overlap) {
        uint2* bufA = agg;
        uint2* bufB = agg + pxA;
        AggArgs aH, a1, a2, a3;
        int nH = build(12, 15, aH);
        int n1 = build(0, 12, a1);
        int n2 = build(15, 19, a2);
        int n3 = build(19, 21, a3);

        agg_all<<<nH, 256, 0, stream>>>(x, wT, bufA, aH);
        fused_k<12, 15><<<n1 + RZ_GRID, 256, 0, stream>>>(
            x, wT, bufB, a1, n1, bufA, wtbl, itbl, out, 0);
        fused_k<0, 12><<<n2 + RZ_GRID, 256, 0, stream>>>(
            x, wT, bufA, a2, n2, bufB, wtbl, itbl, out, 1);
        fused_k<15, 19><<<n3 + RZ_GRID, 256, 0, stream>>>(
            x, wT, bufB, a3, n3, bufA, wtbl, itbl, out, 1);
        resize_static<19, 21><<<RZ_GRID, 256, 0, stream>>>(
            bufB, wtbl, itbl, out, 1);
    } else {
        // Serial fallback: same 4 groups, single buffer.
        AggArgs aa;
        int nb;
        nb = build(12, 15, aa);
        agg_all<<<nb, 256, 0, stream>>>(x, wT, agg, aa);
        resize_static<12, 15><<<RZ_GRID, 256, 0, stream>>>(agg, wtbl, itbl, out, 0);
        nb = build(0, 12, aa);
        agg_all<<<nb, 256, 0, stream>>>(x, wT, agg, aa);
        resize_static<0, 12><<<RZ_GRID, 256, 0, stream>>>(agg, wtbl, itbl, out, 1);
        nb = build(15, 19, aa);
        agg_all<<<nb, 256, 0, stream>>>(x, wT, agg, aa);
        resize_static<15, 19><<<RZ_GRID, 256, 0, stream>>>(agg, wtbl, itbl, out, 1);
        nb = build(19, 21, aa);
        agg_all<<<nb, 256, 0, stream>>>(x, wT, agg, aa);
        resize_static<19, 21><<<RZ_GRID, 256, 0, stream>>>(agg, wtbl, itbl, out, 1);
    }
    (void)in_sizes; (void)n_in; (void)out_size;
}